// Round 1
// baseline (1645.798 us; speedup 1.0000x reference)
//
#include <hip/hip_runtime.h>
#include <math.h>

// ---------------------------------------------------------------------------
// GCRN-GRU with H0=0 collapses to:
//   Xh = x@pre_w + pre_b
//   LX = lap(Xh)            (lap = scatter_add(dst, w[e]*Xh[src]), w=-dinv_s*dinv_d)
//   Z  = sigmoid(Xh@Wx[0,0] + LX@Wx[0,1] + bx0 + bh0)
//   Ht = tanh   (Xh@Wx[2,0] + LX@Wx[2,1] + bx2 + bh2)
//   h  = relu((1-Z)*Ht)
//   out[i] = dot(h[a]*h[b], post_w[:,0]+post_w[:,1]) + post_b[0]+post_b[1]
// Wh and Wx[1] (R gate) are dead code.
// ---------------------------------------------------------------------------

__global__ __launch_bounds__(256) void deg_kernel(const int* __restrict__ ei, int* __restrict__ deg, int E) {
  int i = blockIdx.x * 256 + threadIdx.x;
  if (i < E) atomicAdd(&deg[ei[i]], 1);
}

__global__ __launch_bounds__(256) void dinv_kernel(const int* __restrict__ deg, float* __restrict__ dinv, int N) {
  int i = blockIdx.x * 256 + threadIdx.x;
  if (i < N) {
    int d = deg[i];
    dinv[i] = d > 0 ? rsqrtf((float)d) : 0.0f;
  }
}

// Xh = x @ W(128x128) + b.  Block: 64 rows x 128 cols, thread: 4 rows x 8 cols.
__global__ __launch_bounds__(256) void gemm1_kernel(const float* __restrict__ x, const float* __restrict__ W,
                                                    const float* __restrict__ bias, float* __restrict__ out, int N) {
  __shared__ float Bs[128 * 128];   // full weight, 64 KB
  __shared__ float As[16 * 64];     // A chunk transposed [k][m], 4 KB
  const int t = threadIdx.x;
  const int r0 = blockIdx.x * 64;
  const int tr = t >> 4, tc = t & 15;
  const int m0 = tr * 4, c0 = tc * 4;   // cols handled: {c0..c0+3} and {64+c0..64+c0+3}

#pragma unroll
  for (int i = 0; i < 16; ++i) {
    int idx = i * 1024 + t * 4;
    *(float4*)&Bs[idx] = *(const float4*)&W[idx];
  }

  float acc[4][8];
#pragma unroll
  for (int r = 0; r < 4; ++r)
#pragma unroll
    for (int c = 0; c < 8; ++c) acc[r][c] = 0.0f;

  const int lm = t & 63, lq = t >> 6;   // loader: row lm, k-quad lq
  __syncthreads();

  for (int kc = 0; kc < 8; ++kc) {
    int row = r0 + lm;
    float4 v = make_float4(0.f, 0.f, 0.f, 0.f);
    if (row < N) v = *(const float4*)&x[row * 128 + kc * 16 + lq * 4];
    __syncthreads();
    As[(lq * 4 + 0) * 64 + lm] = v.x;
    As[(lq * 4 + 1) * 64 + lm] = v.y;
    As[(lq * 4 + 2) * 64 + lm] = v.z;
    As[(lq * 4 + 3) * 64 + lm] = v.w;
    __syncthreads();
#pragma unroll
    for (int k = 0; k < 16; ++k) {
      float4 a = *(float4*)&As[k * 64 + m0];
      const float* brow = &Bs[(kc * 16 + k) * 128];
      float4 b0 = *(float4*)&brow[c0];
      float4 b1 = *(float4*)&brow[64 + c0];
      float av[4] = {a.x, a.y, a.z, a.w};
      float bv[8] = {b0.x, b0.y, b0.z, b0.w, b1.x, b1.y, b1.z, b1.w};
#pragma unroll
      for (int r = 0; r < 4; ++r)
#pragma unroll
        for (int c = 0; c < 8; ++c) acc[r][c] += av[r] * bv[c];
    }
  }

#pragma unroll
  for (int r = 0; r < 4; ++r) {
    int row = r0 + m0 + r;
    if (row >= N) continue;
    float4 o0, o1;
    o0.x = acc[r][0] + bias[c0 + 0];
    o0.y = acc[r][1] + bias[c0 + 1];
    o0.z = acc[r][2] + bias[c0 + 2];
    o0.w = acc[r][3] + bias[c0 + 3];
    o1.x = acc[r][4] + bias[64 + c0 + 0];
    o1.y = acc[r][5] + bias[64 + c0 + 1];
    o1.z = acc[r][6] + bias[64 + c0 + 2];
    o1.w = acc[r][7] + bias[64 + c0 + 3];
    *(float4*)&out[row * 128 + c0] = o0;
    *(float4*)&out[row * 128 + 64 + c0] = o1;
  }
}

// LX[dst] += w * Xh[src], w = -dinv[src]*dinv[dst].  32 threads/edge, float4 each.
__global__ __launch_bounds__(256) void lap_kernel(const float* __restrict__ Xh, const int* __restrict__ ei,
                                                  const float* __restrict__ dinv, float* __restrict__ LX, int E) {
  int gid = blockIdx.x * 256 + threadIdx.x;
  int e = gid >> 5;
  if (e >= E) return;
  int c = (gid & 31) * 4;
  int s = ei[e], d = ei[E + e];
  float w = -dinv[s] * dinv[d];
  float4 v = *(const float4*)&Xh[s * 128 + c];
  float* p = &LX[d * 128 + c];
  unsafeAtomicAdd(p + 0, w * v.x);
  unsafeAtomicAdd(p + 1, w * v.y);
  unsafeAtomicAdd(p + 2, w * v.z);
  unsafeAtomicAdd(p + 3, w * v.w);
}

// Fused: Z/Ht GEMMs + activations. Writes h in-place over Xh.
// Block: 32 rows x 128 cols (both gates), thread: 2 rows x 8 cols x {z,h}.
__global__ __launch_bounds__(256) void gemm2_kernel(float* __restrict__ Xh, const float* __restrict__ LX,
                                                    const float* __restrict__ Wx, const float* __restrict__ bx,
                                                    const float* __restrict__ bh, int N) {
  __shared__ float Bzs[32 * 128];   // 16 KB
  __shared__ float Bhs[32 * 128];   // 16 KB
  __shared__ float As[32 * 32];     // 4 KB, [k][m]
  const int t = threadIdx.x;
  const int r0 = blockIdx.x * 32;
  const int tr = t >> 4, tc = t & 15;
  const int m0 = tr * 2, c0 = tc * 4;
  const int am = t & 31, aq = t >> 5;   // A loader: row am, k-quad aq (0..7)

  float accz[2][8], acch[2][8];
#pragma unroll
  for (int r = 0; r < 2; ++r)
#pragma unroll
    for (int c = 0; c < 8; ++c) { accz[r][c] = 0.0f; acch[r][c] = 0.0f; }

  for (int half = 0; half < 2; ++half) {
    const float* __restrict__ A = half ? LX : Xh;
    const float* __restrict__ Wz = Wx + (half ? 16384 : 0);            // Wx[0][half]
    const float* __restrict__ Wt = Wx + 65536 + (half ? 16384 : 0);    // Wx[2][half]
    for (int kc = 0; kc < 4; ++kc) {
      int row = r0 + am;
      float4 av = make_float4(0.f, 0.f, 0.f, 0.f);
      if (row < N) av = *(const float4*)&A[row * 128 + kc * 32 + aq * 4];
      __syncthreads();
      As[(aq * 4 + 0) * 32 + am] = av.x;
      As[(aq * 4 + 1) * 32 + am] = av.y;
      As[(aq * 4 + 2) * 32 + am] = av.z;
      As[(aq * 4 + 3) * 32 + am] = av.w;
#pragma unroll
      for (int i = 0; i < 4; ++i) {
        int idx = i * 1024 + t * 4;
        *(float4*)&Bzs[idx] = *(const float4*)&Wz[kc * 4096 + idx];
        *(float4*)&Bhs[idx] = *(const float4*)&Wt[kc * 4096 + idx];
      }
      __syncthreads();
#pragma unroll
      for (int k = 0; k < 32; ++k) {
        float2 a = *(float2*)&As[k * 32 + m0];
        const float* bz = &Bzs[k * 128];
        const float* bt = &Bhs[k * 128];
        float4 bz0 = *(float4*)&bz[c0];
        float4 bz1 = *(float4*)&bz[64 + c0];
        float4 bt0 = *(float4*)&bt[c0];
        float4 bt1 = *(float4*)&bt[64 + c0];
        float av2[2] = {a.x, a.y};
        float bzv[8] = {bz0.x, bz0.y, bz0.z, bz0.w, bz1.x, bz1.y, bz1.z, bz1.w};
        float btv[8] = {bt0.x, bt0.y, bt0.z, bt0.w, bt1.x, bt1.y, bt1.z, bt1.w};
#pragma unroll
        for (int r = 0; r < 2; ++r)
#pragma unroll
          for (int c = 0; c < 8; ++c) {
            accz[r][c] += av2[r] * bzv[c];
            acch[r][c] += av2[r] * btv[c];
          }
      }
    }
  }

#pragma unroll
  for (int r = 0; r < 2; ++r) {
    int row = r0 + m0 + r;
    if (row >= N) continue;
#pragma unroll
    for (int g = 0; g < 2; ++g) {
      float4 o;
#pragma unroll
      for (int j = 0; j < 4; ++j) {
        int c = g * 64 + c0 + j;
        float z = accz[r][g * 4 + j] + bx[c] + bh[c];
        float hp = acch[r][g * 4 + j] + bx[256 + c] + bh[256 + c];
        float zs = 1.0f / (1.0f + __expf(-z));
        float th = tanhf(hp);
        float val = (1.0f - zs) * th;
        ((float*)&o)[j] = fmaxf(val, 0.0f);
      }
      *(float4*)&Xh[row * 128 + g * 64 + c0] = o;
    }
  }
}

// out[i] = dot(h[a]*h[b], pw) + pb.  16 lanes/edge, 8 k each.
__global__ __launch_bounds__(256) void decoder_kernel(const float* __restrict__ h, const int* __restrict__ eli,
                                                      const float* __restrict__ post_w, const float* __restrict__ post_b,
                                                      float* __restrict__ out, int M) {
  int t = threadIdx.x;
  int i = blockIdx.x * 16 + (t >> 4);
  int l = t & 15;
  if (i >= M) return;
  int a = eli[i], b = eli[M + i];
  int k = l * 8;
  const float4* ha = (const float4*)&h[a * 128 + k];
  const float4* hb = (const float4*)&h[b * 128 + k];
  float4 ha0 = ha[0], ha1 = ha[1];
  float4 hb0 = hb[0], hb1 = hb[1];
  const float4* pwp = (const float4*)&post_w[k * 2];  // post_w is [128][2] row-major
  float4 p0 = pwp[0], p1 = pwp[1], p2 = pwp[2], p3 = pwp[3];
  float s = 0.0f;
  s += ha0.x * hb0.x * (p0.x + p0.y);
  s += ha0.y * hb0.y * (p0.z + p0.w);
  s += ha0.z * hb0.z * (p1.x + p1.y);
  s += ha0.w * hb0.w * (p1.z + p1.w);
  s += ha1.x * hb1.x * (p2.x + p2.y);
  s += ha1.y * hb1.y * (p2.z + p2.w);
  s += ha1.z * hb1.z * (p3.x + p3.y);
  s += ha1.w * hb1.w * (p3.z + p3.w);
#pragma unroll
  for (int off = 8; off; off >>= 1) s += __shfl_xor(s, off);
  if (l == 0) out[i] = s + post_b[0] + post_b[1];
}

extern "C" void kernel_launch(void* const* d_in, const int* in_sizes, int n_in,
                              void* d_out, int out_size, void* d_ws, size_t ws_size,
                              hipStream_t stream) {
  const float* x      = (const float*)d_in[0];
  const int*   ei     = (const int*)d_in[1];
  const int*   eli    = (const int*)d_in[2];
  const float* pre_w  = (const float*)d_in[3];
  const float* pre_b  = (const float*)d_in[4];
  const float* Wx     = (const float*)d_in[5];
  const float* bx     = (const float*)d_in[6];
  // d_in[7] (Wh) is dead code: only its bias bh survives H0=0.
  const float* bh     = (const float*)d_in[8];
  const float* post_w = (const float*)d_in[9];
  const float* post_b = (const float*)d_in[10];
  float* out = (float*)d_out;

  const int N = in_sizes[0] / 128;
  const int E = in_sizes[1] / 2;
  const int M = in_sizes[2] / 2;

  char* ws = (char*)d_ws;
  int*   deg  = (int*)ws;                                   // N ints
  float* dinv = (float*)(ws + 262144);                      // N floats
  float* Xh   = (float*)(ws + 524288);                      // N*128 floats (h written in-place)
  float* LX   = (float*)(ws + 524288 + (size_t)N * 512);    // N*128 floats

  hipMemsetAsync(deg, 0, (size_t)N * 4, stream);
  hipMemsetAsync(LX, 0, (size_t)N * 512, stream);

  deg_kernel<<<(E + 255) / 256, 256, 0, stream>>>(ei, deg, E);
  dinv_kernel<<<(N + 255) / 256, 256, 0, stream>>>(deg, dinv, N);
  gemm1_kernel<<<(N + 63) / 64, 256, 0, stream>>>(x, pre_w, pre_b, Xh, N);
  lap_kernel<<<(int)(((long long)E * 32 + 255) / 256), 256, 0, stream>>>(Xh, ei, dinv, LX, E);
  gemm2_kernel<<<(N + 31) / 32, 256, 0, stream>>>(Xh, LX, Wx, bx, bh, N);
  decoder_kernel<<<(M + 15) / 16, 256, 0, stream>>>(Xh, eli, post_w, post_b, out, M);
}

// Round 2
// 427.212 us; speedup vs baseline: 3.8524x; 3.8524x over previous
//
#include <hip/hip_runtime.h>
#include <math.h>

// ---------------------------------------------------------------------------
// GCRN-GRU with H0=0 collapses to:
//   Xh = x@pre_w + pre_b
//   LX = lap(Xh)            (lap = scatter_add(dst, w[e]*Xh[src]), w=-dinv_s*dinv_d)
//   Z  = sigmoid(Xh@Wx[0,0] + LX@Wx[0,1] + bx0 + bh0)
//   Ht = tanh   (Xh@Wx[2,0] + LX@Wx[2,1] + bx2 + bh2)
//   h  = relu((1-Z)*Ht)
//   out[i] = dot(h[a]*h[b], post_w[:,0]+post_w[:,1]) + post_b[0]+post_b[1]
// Wh and Wx[1] (R gate) are dead code.
//
// R2: replace atomic scatter lap (102M f32 atomics, 76 G/s bound) with
// bucket-by-dst + gather lap (one wave per dst node, register accumulate).
// ---------------------------------------------------------------------------

#define CAP 64          // bucket capacity per node; Poisson(16) => P(>64) ~ 1e-19
#define OVF_MAX 8192

__global__ __launch_bounds__(256) void deg_kernel(const int* __restrict__ ei, int* __restrict__ deg, int E) {
  int i = blockIdx.x * 256 + threadIdx.x;
  if (i < E) atomicAdd(&deg[ei[i]], 1);   // src histogram (for dinv)
}

__global__ __launch_bounds__(256) void dinv_kernel(const int* __restrict__ deg, float* __restrict__ dinv, int N) {
  int i = blockIdx.x * 256 + threadIdx.x;
  if (i < N) {
    int d = deg[i];
    dinv[i] = d > 0 ? rsqrtf((float)d) : 0.0f;
  }
}

// Bucket edges by dst. cur[d] ends up holding full in-degree of d.
__global__ __launch_bounds__(256) void scatter_kernel(const int* __restrict__ ei, int* __restrict__ cur,
                                                      int* __restrict__ bucket, int* __restrict__ ovfn,
                                                      int* __restrict__ ovf, int E) {
  int i = blockIdx.x * 256 + threadIdx.x;
  if (i >= E) return;
  int s = ei[i], d = ei[E + i];
  int pos = atomicAdd(&cur[d], 1);
  if (pos < CAP) {
    bucket[d * CAP + pos] = s;
  } else {
    int k = atomicAdd(ovfn, 1);
    if (k < OVF_MAX) { ovf[2 * k] = s; ovf[2 * k + 1] = d; }
  }
}

// Xh = x @ W(128x128) + b.  Block: 64 rows x 128 cols, thread: 4 rows x 8 cols.
__global__ __launch_bounds__(256) void gemm1_kernel(const float* __restrict__ x, const float* __restrict__ W,
                                                    const float* __restrict__ bias, float* __restrict__ out, int N) {
  __shared__ float Bs[128 * 128];   // full weight, 64 KB
  __shared__ float As[16 * 64];     // A chunk transposed [k][m], 4 KB
  const int t = threadIdx.x;
  const int r0 = blockIdx.x * 64;
  const int tr = t >> 4, tc = t & 15;
  const int m0 = tr * 4, c0 = tc * 4;

#pragma unroll
  for (int i = 0; i < 16; ++i) {
    int idx = i * 1024 + t * 4;
    *(float4*)&Bs[idx] = *(const float4*)&W[idx];
  }

  float acc[4][8];
#pragma unroll
  for (int r = 0; r < 4; ++r)
#pragma unroll
    for (int c = 0; c < 8; ++c) acc[r][c] = 0.0f;

  const int lm = t & 63, lq = t >> 6;
  __syncthreads();

  for (int kc = 0; kc < 8; ++kc) {
    int row = r0 + lm;
    float4 v = make_float4(0.f, 0.f, 0.f, 0.f);
    if (row < N) v = *(const float4*)&x[row * 128 + kc * 16 + lq * 4];
    __syncthreads();
    As[(lq * 4 + 0) * 64 + lm] = v.x;
    As[(lq * 4 + 1) * 64 + lm] = v.y;
    As[(lq * 4 + 2) * 64 + lm] = v.z;
    As[(lq * 4 + 3) * 64 + lm] = v.w;
    __syncthreads();
#pragma unroll
    for (int k = 0; k < 16; ++k) {
      float4 a = *(float4*)&As[k * 64 + m0];
      const float* brow = &Bs[(kc * 16 + k) * 128];
      float4 b0 = *(float4*)&brow[c0];
      float4 b1 = *(float4*)&brow[64 + c0];
      float av[4] = {a.x, a.y, a.z, a.w};
      float bv[8] = {b0.x, b0.y, b0.z, b0.w, b1.x, b1.y, b1.z, b1.w};
#pragma unroll
      for (int r = 0; r < 4; ++r)
#pragma unroll
        for (int c = 0; c < 8; ++c) acc[r][c] += av[r] * bv[c];
    }
  }

#pragma unroll
  for (int r = 0; r < 4; ++r) {
    int row = r0 + m0 + r;
    if (row >= N) continue;
    float4 o0, o1;
    o0.x = acc[r][0] + bias[c0 + 0];
    o0.y = acc[r][1] + bias[c0 + 1];
    o0.z = acc[r][2] + bias[c0 + 2];
    o0.w = acc[r][3] + bias[c0 + 3];
    o1.x = acc[r][4] + bias[64 + c0 + 0];
    o1.y = acc[r][5] + bias[64 + c0 + 1];
    o1.z = acc[r][6] + bias[64 + c0 + 2];
    o1.w = acc[r][7] + bias[64 + c0 + 3];
    *(float4*)&out[row * 128 + c0] = o0;
    *(float4*)&out[row * 128 + 64 + c0] = o1;
  }
}

// Gather lap: one wave per dst node. Prefetch src indices coalesced into lanes,
// broadcast with shuffles, accumulate sum(dinv[s]*Xh[s]) in float2/lane, then
// scale by -dinv[d] and store the full 128-wide row coalesced.
__global__ __launch_bounds__(256) void lap_gather_kernel(const float* __restrict__ Xh, const int* __restrict__ bucket,
                                                         const int* __restrict__ cur, const float* __restrict__ dinv,
                                                         float* __restrict__ LX, int N) {
  int node = (blockIdx.x * 256 + threadIdx.x) >> 6;
  int lane = threadIdx.x & 63;
  if (node >= N) return;
  int n = cur[node];
  if (n > CAP) n = CAP;
  int s_l = 0;
  float w_l = 0.0f;
  if (lane < n) {
    s_l = bucket[node * CAP + lane];   // coalesced
    w_l = dinv[s_l];
  }
  float2 acc = make_float2(0.0f, 0.0f);
  for (int j = 0; j < n; ++j) {
    int s = __shfl(s_l, j);
    float ws = __shfl(w_l, j);
    float2 v = *(const float2*)&Xh[(size_t)s * 128 + lane * 2];
    acc.x += ws * v.x;
    acc.y += ws * v.y;
  }
  float wd = -dinv[node];
  acc.x *= wd;
  acc.y *= wd;
  *(float2*)&LX[(size_t)node * 128 + lane * 2] = acc;
}

// Fallback for bucket overflow (normally 0 edges): atomic adds on top of LX.
__global__ __launch_bounds__(256) void ovf_kernel(const float* __restrict__ Xh, const int* __restrict__ ovfn,
                                                  const int* __restrict__ ovf, const float* __restrict__ dinv,
                                                  float* __restrict__ LX) {
  int count = *ovfn;
  if (count > OVF_MAX) count = OVF_MAX;
  long long total = (long long)count * 32;
  for (long long idx = blockIdx.x * 256 + threadIdx.x; idx < total; idx += (long long)gridDim.x * 256) {
    int e = (int)(idx >> 5);
    int c = ((int)idx & 31) * 4;
    int s = ovf[2 * e], d = ovf[2 * e + 1];
    float w = -dinv[s] * dinv[d];
    float4 v = *(const float4*)&Xh[s * 128 + c];
    float* p = &LX[d * 128 + c];
    unsafeAtomicAdd(p + 0, w * v.x);
    unsafeAtomicAdd(p + 1, w * v.y);
    unsafeAtomicAdd(p + 2, w * v.z);
    unsafeAtomicAdd(p + 3, w * v.w);
  }
}

// Fused: Z/Ht GEMMs + activations. Writes h in-place over Xh.
__global__ __launch_bounds__(256) void gemm2_kernel(float* __restrict__ Xh, const float* __restrict__ LX,
                                                    const float* __restrict__ Wx, const float* __restrict__ bx,
                                                    const float* __restrict__ bh, int N) {
  __shared__ float Bzs[32 * 128];
  __shared__ float Bhs[32 * 128];
  __shared__ float As[32 * 32];
  const int t = threadIdx.x;
  const int r0 = blockIdx.x * 32;
  const int tr = t >> 4, tc = t & 15;
  const int m0 = tr * 2, c0 = tc * 4;
  const int am = t & 31, aq = t >> 5;

  float accz[2][8], acch[2][8];
#pragma unroll
  for (int r = 0; r < 2; ++r)
#pragma unroll
    for (int c = 0; c < 8; ++c) { accz[r][c] = 0.0f; acch[r][c] = 0.0f; }

  for (int half = 0; half < 2; ++half) {
    const float* __restrict__ A = half ? LX : Xh;
    const float* __restrict__ Wz = Wx + (half ? 16384 : 0);
    const float* __restrict__ Wt = Wx + 65536 + (half ? 16384 : 0);
    for (int kc = 0; kc < 4; ++kc) {
      int row = r0 + am;
      float4 av = make_float4(0.f, 0.f, 0.f, 0.f);
      if (row < N) av = *(const float4*)&A[row * 128 + kc * 32 + aq * 4];
      __syncthreads();
      As[(aq * 4 + 0) * 32 + am] = av.x;
      As[(aq * 4 + 1) * 32 + am] = av.y;
      As[(aq * 4 + 2) * 32 + am] = av.z;
      As[(aq * 4 + 3) * 32 + am] = av.w;
#pragma unroll
      for (int i = 0; i < 4; ++i) {
        int idx = i * 1024 + t * 4;
        *(float4*)&Bzs[idx] = *(const float4*)&Wz[kc * 4096 + idx];
        *(float4*)&Bhs[idx] = *(const float4*)&Wt[kc * 4096 + idx];
      }
      __syncthreads();
#pragma unroll
      for (int k = 0; k < 32; ++k) {
        float2 a = *(float2*)&As[k * 32 + m0];
        const float* bz = &Bzs[k * 128];
        const float* bt = &Bhs[k * 128];
        float4 bz0 = *(float4*)&bz[c0];
        float4 bz1 = *(float4*)&bz[64 + c0];
        float4 bt0 = *(float4*)&bt[c0];
        float4 bt1 = *(float4*)&bt[64 + c0];
        float av2[2] = {a.x, a.y};
        float bzv[8] = {bz0.x, bz0.y, bz0.z, bz0.w, bz1.x, bz1.y, bz1.z, bz1.w};
        float btv[8] = {bt0.x, bt0.y, bt0.z, bt0.w, bt1.x, bt1.y, bt1.z, bt1.w};
#pragma unroll
        for (int r = 0; r < 2; ++r)
#pragma unroll
          for (int c = 0; c < 8; ++c) {
            accz[r][c] += av2[r] * bzv[c];
            acch[r][c] += av2[r] * btv[c];
          }
      }
    }
  }

#pragma unroll
  for (int r = 0; r < 2; ++r) {
    int row = r0 + m0 + r;
    if (row >= N) continue;
#pragma unroll
    for (int g = 0; g < 2; ++g) {
      float4 o;
#pragma unroll
      for (int j = 0; j < 4; ++j) {
        int c = g * 64 + c0 + j;
        float z = accz[r][g * 4 + j] + bx[c] + bh[c];
        float hp = acch[r][g * 4 + j] + bx[256 + c] + bh[256 + c];
        float zs = 1.0f / (1.0f + __expf(-z));
        float th = tanhf(hp);
        float val = (1.0f - zs) * th;
        ((float*)&o)[j] = fmaxf(val, 0.0f);
      }
      *(float4*)&Xh[row * 128 + g * 64 + c0] = o;
    }
  }
}

// out[i] = dot(h[a]*h[b], pw) + pb.  16 lanes/edge, 8 k each.
__global__ __launch_bounds__(256) void decoder_kernel(const float* __restrict__ h, const int* __restrict__ eli,
                                                      const float* __restrict__ post_w, const float* __restrict__ post_b,
                                                      float* __restrict__ out, int M) {
  int t = threadIdx.x;
  int i = blockIdx.x * 16 + (t >> 4);
  int l = t & 15;
  if (i >= M) return;
  int a = eli[i], b = eli[M + i];
  int k = l * 8;
  const float4* ha = (const float4*)&h[a * 128 + k];
  const float4* hb = (const float4*)&h[b * 128 + k];
  float4 ha0 = ha[0], ha1 = ha[1];
  float4 hb0 = hb[0], hb1 = hb[1];
  const float4* pwp = (const float4*)&post_w[k * 2];
  float4 p0 = pwp[0], p1 = pwp[1], p2 = pwp[2], p3 = pwp[3];
  float s = 0.0f;
  s += ha0.x * hb0.x * (p0.x + p0.y);
  s += ha0.y * hb0.y * (p0.z + p0.w);
  s += ha0.z * hb0.z * (p1.x + p1.y);
  s += ha0.w * hb0.w * (p1.z + p1.w);
  s += ha1.x * hb1.x * (p2.x + p2.y);
  s += ha1.y * hb1.y * (p2.z + p2.w);
  s += ha1.z * hb1.z * (p3.x + p3.y);
  s += ha1.w * hb1.w * (p3.z + p3.w);
#pragma unroll
  for (int off = 8; off; off >>= 1) s += __shfl_xor(s, off);
  if (l == 0) out[i] = s + post_b[0] + post_b[1];
}

extern "C" void kernel_launch(void* const* d_in, const int* in_sizes, int n_in,
                              void* d_out, int out_size, void* d_ws, size_t ws_size,
                              hipStream_t stream) {
  const float* x      = (const float*)d_in[0];
  const int*   ei     = (const int*)d_in[1];
  const int*   eli    = (const int*)d_in[2];
  const float* pre_w  = (const float*)d_in[3];
  const float* pre_b  = (const float*)d_in[4];
  const float* Wx     = (const float*)d_in[5];
  const float* bx     = (const float*)d_in[6];
  const float* bh     = (const float*)d_in[8];
  const float* post_w = (const float*)d_in[9];
  const float* post_b = (const float*)d_in[10];
  float* out = (float*)d_out;

  const int N = in_sizes[0] / 128;
  const int E = in_sizes[1] / 2;
  const int M = in_sizes[2] / 2;

  char* p = (char*)d_ws;
  int*   deg    = (int*)p;    p += (size_t)N * 4;
  int*   cur    = (int*)p;    p += (size_t)N * 4;
  int*   ovfn   = (int*)p;    p += 4096;
  int*   ovf    = (int*)p;    p += 2 * OVF_MAX * 4;
  float* dinv   = (float*)p;  p += (size_t)N * 4;
  int*   bucket = (int*)p;    p += (size_t)N * CAP * 4;
  float* Xh     = (float*)p;  p += (size_t)N * 512;
  float* LX     = (float*)p;

  hipMemsetAsync(deg, 0, (size_t)N * 4, stream);
  hipMemsetAsync(cur, 0, (size_t)N * 4, stream);
  hipMemsetAsync(ovfn, 0, 4, stream);

  deg_kernel<<<(E + 255) / 256, 256, 0, stream>>>(ei, deg, E);
  dinv_kernel<<<(N + 255) / 256, 256, 0, stream>>>(deg, dinv, N);
  scatter_kernel<<<(E + 255) / 256, 256, 0, stream>>>(ei, cur, bucket, ovfn, ovf, E);
  gemm1_kernel<<<(N + 63) / 64, 256, 0, stream>>>(x, pre_w, pre_b, Xh, N);
  lap_gather_kernel<<<(N * 64 + 255) / 256, 256, 0, stream>>>(Xh, bucket, cur, dinv, LX, N);
  ovf_kernel<<<64, 256, 0, stream>>>(Xh, ovfn, ovf, dinv, LX);
  gemm2_kernel<<<(N + 31) / 32, 256, 0, stream>>>(Xh, LX, Wx, bx, bh, N);
  decoder_kernel<<<(M + 15) / 16, 256, 0, stream>>>(Xh, eli, post_w, post_b, out, M);
}

// Round 3
// 297.976 us; speedup vs baseline: 5.5233x; 1.4337x over previous
//
#include <hip/hip_runtime.h>
#include <math.h>

// ---------------------------------------------------------------------------
// GCRN-GRU with H0=0 collapses to:
//   Xh = x@pre_w + pre_b                      (bf16 MFMA GEMM, K=128)
//   LX = lap(Xh)                              (bucket-by-dst gather, bf16)
//   [Z|T]pre = [Xh|LX] @ Bcat (256x256)       (bf16 MFMA GEMM, K=256)
//   h  = relu((1-sigmoid(Zpre))*tanh(Tpre))   (fused epilogue)
//   out[i] = dot(h[a]*h[b], post_w[:,0]+post_w[:,1]) + post_b[0]+post_b[1]
// Wh and Wx[1] (R gate) are dead code.
// Xhb layout: N x 256 bf16 rows = [Xh cols 0..127 | LX cols 128..255].
// Bcat cols permuted so each wave owns matching (z,t) pairs for fused act.
// ---------------------------------------------------------------------------

#define CAP 64
#define OVF_MAX 8192

typedef __attribute__((ext_vector_type(4))) float f32x4;
typedef __attribute__((ext_vector_type(8))) short short8;

static __device__ __forceinline__ unsigned short f2b(float f) {
  union { float f; unsigned u; } v; v.f = f;
  unsigned r = (v.u + 0x7fffu + ((v.u >> 16) & 1u)) >> 16;  // RNE
  return (unsigned short)r;
}
static __device__ __forceinline__ float b2f(unsigned short s) {
  union { unsigned u; float f; } v; v.u = ((unsigned)s) << 16;
  return v.f;
}

// Merged: deg[src]++ histogram + bucket edges by dst.
__global__ __launch_bounds__(256) void scatter_deg_kernel(const int* __restrict__ ei, int* __restrict__ deg,
                                                          int* __restrict__ cur, int* __restrict__ bucket,
                                                          int* __restrict__ ovfn, int* __restrict__ ovf, int E) {
  int i = blockIdx.x * 256 + threadIdx.x;
  if (i >= E) return;
  int s = ei[i], d = ei[E + i];
  atomicAdd(&deg[s], 1);
  int pos = atomicAdd(&cur[d], 1);
  if (pos < CAP) {
    bucket[d * CAP + pos] = s;
  } else {
    int k = atomicAdd(ovfn, 1);
    if (k < OVF_MAX) { ovf[2 * k] = s; ovf[2 * k + 1] = d; }
  }
}

__global__ __launch_bounds__(256) void dinv_kernel(const int* __restrict__ deg, float* __restrict__ dinv, int N) {
  int i = blockIdx.x * 256 + threadIdx.x;
  if (i < N) {
    int d = deg[i];
    dinv[i] = d > 0 ? rsqrtf((float)d) : 0.0f;
  }
}

// Build bf16 weight images (transposed, k-chunk-major) + fused biases.
// Bt1c[kc][col][kk] = pre_w[kc*32+kk][col]                        (kc<4, col<128, kk<32)
// Btc2[kc][cB][kk]: cB decode: cb=cB>>7, r7=cB&127, nw6=r7>>6, u2=r7&63,
//   g=(u2>=32?2:0), hcol=cb*64+nw6*32+(u2&31), k=kc*32+kk, half=k>>7, ki=k&127
//   = Wx[g][half][ki][hcol]
// fb2[cB] = bx[g*128+hcol] + bh[g*128+hcol]
__global__ __launch_bounds__(256) void prep_kernel(const float* __restrict__ pre_w, const float* __restrict__ Wx,
                                                   const float* __restrict__ bx, const float* __restrict__ bh,
                                                   unsigned short* __restrict__ Bt1c, unsigned short* __restrict__ Btc2,
                                                   float* __restrict__ fb2) {
  int e = blockIdx.x * 256 + threadIdx.x;
  if (e < 16384) {
    int kc = e >> 12, r = e & 4095, col = r >> 5, kk = r & 31;
    Bt1c[e] = f2b(pre_w[(kc * 32 + kk) * 128 + col]);
  }
  int e2 = e - 16384;
  if (e2 >= 0 && e2 < 65536) {
    int kc = e2 >> 13, r = e2 & 8191, cB = r >> 5, kk = r & 31;
    int k = kc * 32 + kk, half = k >> 7, ki = k & 127;
    int cb = cB >> 7, r7 = cB & 127, nw6 = r7 >> 6, u2 = r7 & 63;
    int g = (u2 >= 32) ? 2 : 0, hcol = cb * 64 + nw6 * 32 + (u2 & 31);
    Btc2[e2] = f2b(Wx[((g * 2 + half) * 128 + ki) * 128 + hcol]);
  }
  int e3 = e - (16384 + 65536);
  if (e3 >= 0 && e3 < 256) {
    int cB = e3;
    int cb = cB >> 7, r7 = cB & 127, nw6 = r7 >> 6, u2 = r7 & 63;
    int g = (u2 >= 32) ? 2 : 0, hcol = cb * 64 + nw6 * 32 + (u2 & 31);
    fb2[cB] = bx[g * 128 + hcol] + bh[g * 128 + hcol];
  }
}

// Xh = x @ pre_w + pre_b -> bf16 into Xhb cols 0..127 (row stride 256).
// 128x128 block tile, 4 waves in 2x2, wave = 64x64 (4x4 MFMA 16x16x32 tiles).
__global__ __launch_bounds__(256) void gemm1_mfma(const float* __restrict__ x, const unsigned short* __restrict__ Bt1c,
                                                  const float* __restrict__ pre_b, unsigned short* __restrict__ Xhb,
                                                  int N) {
  __shared__ unsigned short As[128 * 40];   // [row][k], pad 32->40 (bank-conflict-free)
  __shared__ unsigned short Bs[128 * 40];   // [col][k]
  const int t = threadIdx.x;
  const int r0 = blockIdx.x * 128;
  const int w = t >> 6, lane = t & 63;
  const int m = lane & 15, q = lane >> 4;
  const int mw = (w >> 1) * 64, nw = (w & 1) * 64;

  f32x4 acc[4][4];
#pragma unroll
  for (int i = 0; i < 4; ++i)
#pragma unroll
    for (int j = 0; j < 4; ++j) acc[i][j] = {0.f, 0.f, 0.f, 0.f};

  const int arow = t >> 1, aseg = t & 1;   // A: 128 rows x 32 fp32; thread covers 16 floats

  for (int kc = 0; kc < 4; ++kc) {
    float4 av[4];
    if (r0 + arow < N) {
      const float* src = &x[(size_t)(r0 + arow) * 128 + kc * 32 + aseg * 16];
#pragma unroll
      for (int i = 0; i < 4; ++i) av[i] = *(const float4*)(src + i * 4);
    } else {
#pragma unroll
      for (int i = 0; i < 4; ++i) av[i] = make_float4(0.f, 0.f, 0.f, 0.f);
    }
    short8 bv0, bv1;
    {
      const char* src = (const char*)Bt1c + (size_t)kc * 8192 + t * 32;
      bv0 = *(const short8*)src;
      bv1 = *(const short8*)(src + 16);
    }
    __syncthreads();
    {
      short8 t0, t1;
#pragma unroll
      for (int i = 0; i < 2; ++i) {
        t0[i * 4 + 0] = (short)f2b(av[i].x); t0[i * 4 + 1] = (short)f2b(av[i].y);
        t0[i * 4 + 2] = (short)f2b(av[i].z); t0[i * 4 + 3] = (short)f2b(av[i].w);
        t1[i * 4 + 0] = (short)f2b(av[i + 2].x); t1[i * 4 + 1] = (short)f2b(av[i + 2].y);
        t1[i * 4 + 2] = (short)f2b(av[i + 2].z); t1[i * 4 + 3] = (short)f2b(av[i + 2].w);
      }
      *(short8*)&As[arow * 40 + aseg * 16] = t0;
      *(short8*)&As[arow * 40 + aseg * 16 + 8] = t1;
      int bcol = t >> 1, boff = (t & 1) * 16;
      *(short8*)&Bs[bcol * 40 + boff] = bv0;
      *(short8*)&Bs[bcol * 40 + boff + 8] = bv1;
    }
    __syncthreads();
    short8 af[4], bf[4];
#pragma unroll
    for (int i = 0; i < 4; ++i) af[i] = *(const short8*)&As[(mw + i * 16 + m) * 40 + q * 8];
#pragma unroll
    for (int j = 0; j < 4; ++j) bf[j] = *(const short8*)&Bs[(nw + j * 16 + m) * 40 + q * 8];
#pragma unroll
    for (int i = 0; i < 4; ++i)
#pragma unroll
      for (int j = 0; j < 4; ++j)
        acc[i][j] = __builtin_amdgcn_mfma_f32_16x16x32_bf16(af[i], bf[j], acc[i][j], 0, 0, 0);
  }

#pragma unroll
  for (int i = 0; i < 4; ++i) {
    int rb = r0 + mw + i * 16 + q * 4;
#pragma unroll
    for (int j = 0; j < 4; ++j) {
      int col = nw + j * 16 + m;
      float bias = pre_b[col];
#pragma unroll
      for (int r = 0; r < 4; ++r) {
        int row = rb + r;
        if (row < N) Xhb[(size_t)row * 256 + col] = f2b(acc[i][j][r] + bias);
      }
    }
  }
}

// Gather lap over bf16 rows: LX[d] = -dinv[d] * sum_s dinv[s]*Xh[s].
// One wave per dst node; writes bf16 into Xhb cols 128..255.
__global__ __launch_bounds__(256) void lap_gather(unsigned short* __restrict__ Xhb, const int* __restrict__ bucket,
                                                  const int* __restrict__ cur, const float* __restrict__ dinv, int N) {
  int node = (blockIdx.x * 256 + threadIdx.x) >> 6;
  int lane = threadIdx.x & 63;
  if (node >= N) return;
  int n = cur[node];
  if (n > CAP) n = CAP;
  int s_l = 0;
  float w_l = 0.0f;
  if (lane < n) {
    s_l = bucket[node * CAP + lane];
    w_l = dinv[s_l];
  }
  float ax = 0.f, ay = 0.f;
  for (int j = 0; j < n; ++j) {
    int s = __shfl(s_l, j);
    float ws = __shfl(w_l, j);
    unsigned v = *(const unsigned*)((const char*)Xhb + (size_t)s * 512 + lane * 4);
    union { unsigned u; float f; } lo, hi;
    lo.u = v << 16;
    hi.u = v & 0xffff0000u;
    ax += ws * lo.f;
    ay += ws * hi.f;
  }
  float wd = -dinv[node];
  unsigned o = (unsigned)f2b(ax * wd) | ((unsigned)f2b(ay * wd) << 16);
  *(unsigned*)((char*)Xhb + (size_t)node * 512 + 256 + lane * 4) = o;
}

// Bucket-overflow fallback (statistically never fires at Poisson(16), CAP=64).
__global__ __launch_bounds__(256) void ovf_kernel(unsigned short* __restrict__ Xhb, const int* __restrict__ ovfn,
                                                  const int* __restrict__ ovf, const float* __restrict__ dinv) {
  int count = *ovfn;
  if (count > OVF_MAX) count = OVF_MAX;
  int e = blockIdx.x * 256 + threadIdx.x;
  if (e >= count) return;
  int s = ovf[2 * e], d = ovf[2 * e + 1];
  float w = -dinv[s] * dinv[d];
  for (int c = 0; c < 128; ++c) {
    float add = w * b2f(Xhb[(size_t)s * 256 + c]);
    unsigned short* p = &Xhb[(size_t)d * 256 + 128 + c];
    *p = f2b(b2f(*p) + add);
  }
}

// [Z|T]pre = Xhb(Nx256 bf16) @ Btc2, fused sigmoid/tanh/relu epilogue -> h fp32.
// Grid: RB*2 blocks (rb=row block 128, cb=col half). Wave nw owns z tiles (j=0,1)
// and t tiles (j=2,3) for the SAME 32 h-cols -> activation needs no data movement.
__global__ __launch_bounds__(256) void gemm2_mfma(const unsigned short* __restrict__ Xhb,
                                                  const unsigned short* __restrict__ Btc2,
                                                  const float* __restrict__ fb2, float* __restrict__ h, int N) {
  __shared__ unsigned short As[128 * 40];
  __shared__ unsigned short Bs[128 * 40];
  const int t = threadIdx.x;
  const int rb = blockIdx.x >> 1, cb = blockIdx.x & 1;
  const int r0 = rb * 128;
  const int w = t >> 6, lane = t & 63;
  const int m = lane & 15, q = lane >> 4;
  const int mw = (w >> 1) * 64, nw = (w & 1) * 64;

  f32x4 acc[4][4];
#pragma unroll
  for (int i = 0; i < 4; ++i)
#pragma unroll
    for (int j = 0; j < 4; ++j) acc[i][j] = {0.f, 0.f, 0.f, 0.f};

  const int arow = t >> 1;
  const int aoff = (t & 1) * 32;   // bytes within 64B row-chunk

  for (int kc = 0; kc < 8; ++kc) {
    short8 av0, av1, bv0, bv1;
    {
      // rows r0..r0+127 may exceed N on the last rb; Xhb is padded to RB*128 rows.
      const char* asrc = (const char*)Xhb + (size_t)(r0 + arow) * 512 + kc * 64 + aoff;
      av0 = *(const short8*)asrc;
      av1 = *(const short8*)(asrc + 16);
      const char* bsrc = (const char*)Btc2 + (size_t)kc * 16384 + (size_t)cb * 8192 + t * 32;
      bv0 = *(const short8*)bsrc;
      bv1 = *(const short8*)(bsrc + 16);
    }
    __syncthreads();
    *(short8*)&As[arow * 40 + (aoff >> 1)] = av0;
    *(short8*)&As[arow * 40 + (aoff >> 1) + 8] = av1;
    {
      int bcol = t >> 1, boff = (t & 1) * 16;
      *(short8*)&Bs[bcol * 40 + boff] = bv0;
      *(short8*)&Bs[bcol * 40 + boff + 8] = bv1;
    }
    __syncthreads();
    short8 af[4], bf[4];
#pragma unroll
    for (int i = 0; i < 4; ++i) af[i] = *(const short8*)&As[(mw + i * 16 + m) * 40 + q * 8];
#pragma unroll
    for (int j = 0; j < 4; ++j) bf[j] = *(const short8*)&Bs[(nw + j * 16 + m) * 40 + q * 8];
#pragma unroll
    for (int i = 0; i < 4; ++i)
#pragma unroll
      for (int j = 0; j < 4; ++j)
        acc[i][j] = __builtin_amdgcn_mfma_f32_16x16x32_bf16(af[i], bf[j], acc[i][j], 0, 0, 0);
  }

#pragma unroll
  for (int i = 0; i < 4; ++i) {
    int rbase = r0 + mw + i * 16 + q * 4;
#pragma unroll
    for (int jz = 0; jz < 2; ++jz) {
      int cBz = cb * 128 + nw + jz * 16 + m;     // z col; t col = cBz + 32
      int hc = cb * 64 + (nw >> 1) + jz * 16 + m;
      float bz = fb2[cBz], bt = fb2[cBz + 32];
#pragma unroll
      for (int r = 0; r < 4; ++r) {
        int row = rbase + r;
        if (row < N) {
          float zp = acc[i][jz][r] + bz;
          float tp = acc[i][jz + 2][r] + bt;
          float zs = 1.0f / (1.0f + __expf(-zp));
          float th = tanhf(tp);
          h[(size_t)row * 128 + hc] = fmaxf((1.0f - zs) * th, 0.0f);
        }
      }
    }
  }
}

// out[i] = dot(h[a]*h[b], pw0+pw1) + pb0+pb1.  16 lanes/edge, 8 k each.
__global__ __launch_bounds__(256) void decoder_kernel(const float* __restrict__ h, const int* __restrict__ eli,
                                                      const float* __restrict__ post_w, const float* __restrict__ post_b,
                                                      float* __restrict__ out, int M) {
  int t = threadIdx.x;
  int i = blockIdx.x * 16 + (t >> 4);
  int l = t & 15;
  if (i >= M) return;
  int a = eli[i], b = eli[M + i];
  int k = l * 8;
  const float4* ha = (const float4*)&h[(size_t)a * 128 + k];
  const float4* hb = (const float4*)&h[(size_t)b * 128 + k];
  float4 ha0 = ha[0], ha1 = ha[1];
  float4 hb0 = hb[0], hb1 = hb[1];
  const float4* pwp = (const float4*)&post_w[k * 2];
  float4 p0 = pwp[0], p1 = pwp[1], p2 = pwp[2], p3 = pwp[3];
  float s = 0.0f;
  s += ha0.x * hb0.x * (p0.x + p0.y);
  s += ha0.y * hb0.y * (p0.z + p0.w);
  s += ha0.z * hb0.z * (p1.x + p1.y);
  s += ha0.w * hb0.w * (p1.z + p1.w);
  s += ha1.x * hb1.x * (p2.x + p2.y);
  s += ha1.y * hb1.y * (p2.z + p2.w);
  s += ha1.z * hb1.z * (p3.x + p3.y);
  s += ha1.w * hb1.w * (p3.z + p3.w);
#pragma unroll
  for (int off = 8; off; off >>= 1) s += __shfl_xor(s, off);
  if (l == 0) out[i] = s + post_b[0] + post_b[1];
}

extern "C" void kernel_launch(void* const* d_in, const int* in_sizes, int n_in,
                              void* d_out, int out_size, void* d_ws, size_t ws_size,
                              hipStream_t stream) {
  const float* x      = (const float*)d_in[0];
  const int*   ei     = (const int*)d_in[1];
  const int*   eli    = (const int*)d_in[2];
  const float* pre_w  = (const float*)d_in[3];
  const float* pre_b  = (const float*)d_in[4];
  const float* Wx     = (const float*)d_in[5];
  const float* bx     = (const float*)d_in[6];
  const float* bh     = (const float*)d_in[8];
  const float* post_w = (const float*)d_in[9];
  const float* post_b = (const float*)d_in[10];
  float* out = (float*)d_out;

  const int N = in_sizes[0] / 128;
  const int E = in_sizes[1] / 2;
  const int M = in_sizes[2] / 2;
  const int RB = (N + 127) / 128;

  char* W = (char*)d_ws;
  size_t o = 0;
  int* deg = (int*)(W + o);  o += (size_t)N * 4;
  int* cur = (int*)(W + o);  o += (size_t)N * 4;
  int* ovfn = (int*)(W + o);
  size_t zbytes = o + 256;   o += 256;
  int* ovf = (int*)(W + o);  o += (size_t)OVF_MAX * 8;
  float* dinv = (float*)(W + o); o += (size_t)N * 4;
  o = (o + 255) & ~(size_t)255;
  int* bucket = (int*)(W + o);   o += (size_t)N * CAP * 4;
  o = (o + 255) & ~(size_t)255;
  unsigned short* Xhb = (unsigned short*)(W + o); o += (size_t)RB * 128 * 512;  // padded rows
  float* h = (float*)(W + o);    o += (size_t)N * 512;
  unsigned short* Bt1c = (unsigned short*)(W + o); o += 32768;
  unsigned short* Btc2 = (unsigned short*)(W + o); o += 131072;
  float* fb2 = (float*)(W + o);  o += 1024;

  hipMemsetAsync(deg, 0, zbytes, stream);
  prep_kernel<<<321, 256, 0, stream>>>(pre_w, Wx, bx, bh, Bt1c, Btc2, fb2);
  scatter_deg_kernel<<<(E + 255) / 256, 256, 0, stream>>>(ei, deg, cur, bucket, ovfn, ovf, E);
  dinv_kernel<<<(N + 255) / 256, 256, 0, stream>>>(deg, dinv, N);
  gemm1_mfma<<<RB, 256, 0, stream>>>(x, Bt1c, pre_b, Xhb, N);
  lap_gather<<<(N + 3) / 4, 256, 0, stream>>>(Xhb, bucket, cur, dinv, N);
  ovf_kernel<<<OVF_MAX / 256, 256, 0, stream>>>(Xhb, ovfn, ovf, dinv);
  gemm2_mfma<<<RB * 2, 256, 0, stream>>>(Xhb, Btc2, fb2, h, N);
  decoder_kernel<<<(M + 15) / 16, 256, 0, stream>>>(h, eli, post_w, post_b, out, M);
}

// Round 4
// 269.656 us; speedup vs baseline: 6.1033x; 1.1050x over previous
//
#include <hip/hip_runtime.h>
#include <math.h>

// ---------------------------------------------------------------------------
// GCRN-GRU with H0=0 collapses to:
//   Xh = x@pre_w + pre_b                      (bf16 MFMA GEMM, K=128)
//   LX = lap(Xh)                              (bucket-by-dst gather, bf16)
//   [Z|T]pre = [Xh|LX] @ Bcat (256x256)       (bf16 MFMA GEMM, K=256)
//   h  = relu((1-sigmoid(Zpre))*tanh(Tpre))   (fused epilogue)
//   out[i] = dot(h[a]*h[b], pwsum) + pbsum
// Wh and Wx[1] (R gate) are dead code.
// R4: lap_gather 8-way MLP unroll (was serial dependent-load chain),
//     nontemporal bucket stores (write-allocate waste 91B/edge -> sector),
//     prep-folded pwsum.
// ---------------------------------------------------------------------------

#define CAP 64
#define OVF_MAX 8192

typedef __attribute__((ext_vector_type(4))) float f32x4;
typedef __attribute__((ext_vector_type(8))) short short8;

static __device__ __forceinline__ unsigned short f2b(float f) {
  union { float f; unsigned u; } v; v.f = f;
  unsigned r = (v.u + 0x7fffu + ((v.u >> 16) & 1u)) >> 16;  // RNE
  return (unsigned short)r;
}
static __device__ __forceinline__ float b2f(unsigned short s) {
  union { unsigned u; float f; } v; v.u = ((unsigned)s) << 16;
  return v.f;
}

// Merged: deg[src]++ histogram + bucket edges by dst (nontemporal stores).
__global__ __launch_bounds__(256) void scatter_deg_kernel(const int* __restrict__ ei, int* __restrict__ deg,
                                                          int* __restrict__ cur, int* __restrict__ bucket,
                                                          int* __restrict__ ovfn, int* __restrict__ ovf, int E) {
  int i = blockIdx.x * 256 + threadIdx.x;
  if (i >= E) return;
  int s = ei[i], d = ei[E + i];
  atomicAdd(&deg[s], 1);
  int pos = atomicAdd(&cur[d], 1);
  if (pos < CAP) {
    __builtin_nontemporal_store(s, &bucket[d * CAP + pos]);
  } else {
    int k = atomicAdd(ovfn, 1);
    if (k < OVF_MAX) { ovf[2 * k] = s; ovf[2 * k + 1] = d; }
  }
}

__global__ __launch_bounds__(256) void dinv_kernel(const int* __restrict__ deg, float* __restrict__ dinv, int N) {
  int i = blockIdx.x * 256 + threadIdx.x;
  if (i < N) {
    int d = deg[i];
    dinv[i] = d > 0 ? rsqrtf((float)d) : 0.0f;
  }
}

// Build bf16 weight images (transposed, k-chunk-major) + fused biases + pwsum.
__global__ __launch_bounds__(256) void prep_kernel(const float* __restrict__ pre_w, const float* __restrict__ Wx,
                                                   const float* __restrict__ bx, const float* __restrict__ bh,
                                                   const float* __restrict__ post_w, const float* __restrict__ post_b,
                                                   unsigned short* __restrict__ Bt1c, unsigned short* __restrict__ Btc2,
                                                   float* __restrict__ fb2, float* __restrict__ pwsum) {
  int e = blockIdx.x * 256 + threadIdx.x;
  if (e < 16384) {
    int kc = e >> 12, r = e & 4095, col = r >> 5, kk = r & 31;
    Bt1c[e] = f2b(pre_w[(kc * 32 + kk) * 128 + col]);
  }
  int e2 = e - 16384;
  if (e2 >= 0 && e2 < 65536) {
    int kc = e2 >> 13, r = e2 & 8191, cB = r >> 5, kk = r & 31;
    int k = kc * 32 + kk, half = k >> 7, ki = k & 127;
    int cb = cB >> 7, r7 = cB & 127, nw6 = r7 >> 6, u2 = r7 & 63;
    int g = (u2 >= 32) ? 2 : 0, hcol = cb * 64 + nw6 * 32 + (u2 & 31);
    Btc2[e2] = f2b(Wx[((g * 2 + half) * 128 + ki) * 128 + hcol]);
  }
  int e3 = e - (16384 + 65536);
  if (e3 >= 0 && e3 < 256) {
    int cB = e3;
    int cb = cB >> 7, r7 = cB & 127, nw6 = r7 >> 6, u2 = r7 & 63;
    int g = (u2 >= 32) ? 2 : 0, hcol = cb * 64 + nw6 * 32 + (u2 & 31);
    fb2[cB] = bx[g * 128 + hcol] + bh[g * 128 + hcol];
  }
  int e4 = e - (16384 + 65536 + 256);
  if (e4 >= 0 && e4 < 128) pwsum[e4] = post_w[2 * e4] + post_w[2 * e4 + 1];
  if (e4 == 128) pwsum[128] = post_b[0] + post_b[1];
}

// Xh = x @ pre_w + pre_b -> bf16 into Xhb cols 0..127 (row stride 256).
__global__ __launch_bounds__(256) void gemm1_mfma(const float* __restrict__ x, const unsigned short* __restrict__ Bt1c,
                                                  const float* __restrict__ pre_b, unsigned short* __restrict__ Xhb,
                                                  int N) {
  __shared__ unsigned short As[128 * 40];
  __shared__ unsigned short Bs[128 * 40];
  const int t = threadIdx.x;
  const int r0 = blockIdx.x * 128;
  const int w = t >> 6, lane = t & 63;
  const int m = lane & 15, q = lane >> 4;
  const int mw = (w >> 1) * 64, nw = (w & 1) * 64;

  f32x4 acc[4][4];
#pragma unroll
  for (int i = 0; i < 4; ++i)
#pragma unroll
    for (int j = 0; j < 4; ++j) acc[i][j] = {0.f, 0.f, 0.f, 0.f};

  const int arow = t >> 1, aseg = t & 1;

  for (int kc = 0; kc < 4; ++kc) {
    float4 av[4];
    if (r0 + arow < N) {
      const float* src = &x[(size_t)(r0 + arow) * 128 + kc * 32 + aseg * 16];
#pragma unroll
      for (int i = 0; i < 4; ++i) av[i] = *(const float4*)(src + i * 4);
    } else {
#pragma unroll
      for (int i = 0; i < 4; ++i) av[i] = make_float4(0.f, 0.f, 0.f, 0.f);
    }
    short8 bv0, bv1;
    {
      const char* src = (const char*)Bt1c + (size_t)kc * 8192 + t * 32;
      bv0 = *(const short8*)src;
      bv1 = *(const short8*)(src + 16);
    }
    __syncthreads();
    {
      short8 t0, t1;
#pragma unroll
      for (int i = 0; i < 2; ++i) {
        t0[i * 4 + 0] = (short)f2b(av[i].x); t0[i * 4 + 1] = (short)f2b(av[i].y);
        t0[i * 4 + 2] = (short)f2b(av[i].z); t0[i * 4 + 3] = (short)f2b(av[i].w);
        t1[i * 4 + 0] = (short)f2b(av[i + 2].x); t1[i * 4 + 1] = (short)f2b(av[i + 2].y);
        t1[i * 4 + 2] = (short)f2b(av[i + 2].z); t1[i * 4 + 3] = (short)f2b(av[i + 2].w);
      }
      *(short8*)&As[arow * 40 + aseg * 16] = t0;
      *(short8*)&As[arow * 40 + aseg * 16 + 8] = t1;
      int bcol = t >> 1, boff = (t & 1) * 16;
      *(short8*)&Bs[bcol * 40 + boff] = bv0;
      *(short8*)&Bs[bcol * 40 + boff + 8] = bv1;
    }
    __syncthreads();
    short8 af[4], bf[4];
#pragma unroll
    for (int i = 0; i < 4; ++i) af[i] = *(const short8*)&As[(mw + i * 16 + m) * 40 + q * 8];
#pragma unroll
    for (int j = 0; j < 4; ++j) bf[j] = *(const short8*)&Bs[(nw + j * 16 + m) * 40 + q * 8];
#pragma unroll
    for (int i = 0; i < 4; ++i)
#pragma unroll
      for (int j = 0; j < 4; ++j)
        acc[i][j] = __builtin_amdgcn_mfma_f32_16x16x32_bf16(af[i], bf[j], acc[i][j], 0, 0, 0);
  }

#pragma unroll
  for (int i = 0; i < 4; ++i) {
    int rb = r0 + mw + i * 16 + q * 4;
#pragma unroll
    for (int j = 0; j < 4; ++j) {
      int col = nw + j * 16 + m;
      float bias = pre_b[col];
#pragma unroll
      for (int r = 0; r < 4; ++r) {
        int row = rb + r;
        if (row < N) Xhb[(size_t)row * 256 + col] = f2b(acc[i][j][r] + bias);
      }
    }
  }
}

// Gather lap: one wave per dst node, 8 loads in flight (MLP unroll).
// Lanes >= n hold s=0/w=0, so the zero-weight tail keeps the loop branch-free.
__global__ __launch_bounds__(256) void lap_gather(unsigned short* __restrict__ Xhb, const int* __restrict__ bucket,
                                                  const int* __restrict__ cur, const float* __restrict__ dinv, int N) {
  int node = (blockIdx.x * 256 + threadIdx.x) >> 6;
  int lane = threadIdx.x & 63;
  if (node >= N) return;
  int n = cur[node];
  if (n > CAP) n = CAP;
  int s_l = 0;
  float w_l = 0.0f;
  if (lane < n) {
    s_l = bucket[node * CAP + lane];
    w_l = dinv[s_l];
  }
  float ax = 0.f, ay = 0.f;
  for (int j = 0; j < n; j += 8) {
    unsigned v[8];
    float ws[8];
#pragma unroll
    for (int u = 0; u < 8; ++u) {
      int s = __shfl(s_l, j + u);
      ws[u] = __shfl(w_l, j + u);
      v[u] = *(const unsigned*)((const char*)Xhb + (size_t)s * 512 + lane * 4);
    }
#pragma unroll
    for (int u = 0; u < 8; ++u) {
      union { unsigned u32; float f; } lo, hi;
      lo.u32 = v[u] << 16;
      hi.u32 = v[u] & 0xffff0000u;
      ax += ws[u] * lo.f;
      ay += ws[u] * hi.f;
    }
  }
  float wd = -dinv[node];
  unsigned o = (unsigned)f2b(ax * wd) | ((unsigned)f2b(ay * wd) << 16);
  *(unsigned*)((char*)Xhb + (size_t)node * 512 + 256 + lane * 4) = o;
}

// Bucket-overflow fallback (statistically never fires at Poisson(16), CAP=64).
__global__ __launch_bounds__(256) void ovf_kernel(unsigned short* __restrict__ Xhb, const int* __restrict__ ovfn,
                                                  const int* __restrict__ ovf, const float* __restrict__ dinv) {
  int count = *ovfn;
  if (count > OVF_MAX) count = OVF_MAX;
  int e = blockIdx.x * 256 + threadIdx.x;
  if (e >= count) return;
  int s = ovf[2 * e], d = ovf[2 * e + 1];
  float w = -dinv[s] * dinv[d];
  for (int c = 0; c < 128; ++c) {
    float add = w * b2f(Xhb[(size_t)s * 256 + c]);
    unsigned short* p = &Xhb[(size_t)d * 256 + 128 + c];
    *p = f2b(b2f(*p) + add);
  }
}

// [Z|T]pre = Xhb(Nx256 bf16) @ Btc2, fused sigmoid/tanh/relu epilogue -> h fp32.
__global__ __launch_bounds__(256) void gemm2_mfma(const unsigned short* __restrict__ Xhb,
                                                  const unsigned short* __restrict__ Btc2,
                                                  const float* __restrict__ fb2, float* __restrict__ h, int N) {
  __shared__ unsigned short As[128 * 40];
  __shared__ unsigned short Bs[128 * 40];
  const int t = threadIdx.x;
  const int rb = blockIdx.x >> 1, cb = blockIdx.x & 1;
  const int r0 = rb * 128;
  const int w = t >> 6, lane = t & 63;
  const int m = lane & 15, q = lane >> 4;
  const int mw = (w >> 1) * 64, nw = (w & 1) * 64;

  f32x4 acc[4][4];
#pragma unroll
  for (int i = 0; i < 4; ++i)
#pragma unroll
    for (int j = 0; j < 4; ++j) acc[i][j] = {0.f, 0.f, 0.f, 0.f};

  const int arow = t >> 1;
  const int aoff = (t & 1) * 32;

  for (int kc = 0; kc < 8; ++kc) {
    short8 av0, av1, bv0, bv1;
    {
      const char* asrc = (const char*)Xhb + (size_t)(r0 + arow) * 512 + kc * 64 + aoff;
      av0 = *(const short8*)asrc;
      av1 = *(const short8*)(asrc + 16);
      const char* bsrc = (const char*)Btc2 + (size_t)kc * 16384 + (size_t)cb * 8192 + t * 32;
      bv0 = *(const short8*)bsrc;
      bv1 = *(const short8*)(bsrc + 16);
    }
    __syncthreads();
    *(short8*)&As[arow * 40 + (aoff >> 1)] = av0;
    *(short8*)&As[arow * 40 + (aoff >> 1) + 8] = av1;
    {
      int bcol = t >> 1, boff = (t & 1) * 16;
      *(short8*)&Bs[bcol * 40 + boff] = bv0;
      *(short8*)&Bs[bcol * 40 + boff + 8] = bv1;
    }
    __syncthreads();
    short8 af[4], bf[4];
#pragma unroll
    for (int i = 0; i < 4; ++i) af[i] = *(const short8*)&As[(mw + i * 16 + m) * 40 + q * 8];
#pragma unroll
    for (int j = 0; j < 4; ++j) bf[j] = *(const short8*)&Bs[(nw + j * 16 + m) * 40 + q * 8];
#pragma unroll
    for (int i = 0; i < 4; ++i)
#pragma unroll
      for (int j = 0; j < 4; ++j)
        acc[i][j] = __builtin_amdgcn_mfma_f32_16x16x32_bf16(af[i], bf[j], acc[i][j], 0, 0, 0);
  }

#pragma unroll
  for (int i = 0; i < 4; ++i) {
    int rbase = r0 + mw + i * 16 + q * 4;
#pragma unroll
    for (int jz = 0; jz < 2; ++jz) {
      int cBz = cb * 128 + nw + jz * 16 + m;
      int hc = cb * 64 + (nw >> 1) + jz * 16 + m;
      float bz = fb2[cBz], bt = fb2[cBz + 32];
#pragma unroll
      for (int r = 0; r < 4; ++r) {
        int row = rbase + r;
        if (row < N) {
          float zp = acc[i][jz][r] + bz;
          float tp = acc[i][jz + 2][r] + bt;
          float zs = 1.0f / (1.0f + __expf(-zp));
          float th = tanhf(tp);
          h[(size_t)row * 128 + hc] = fmaxf((1.0f - zs) * th, 0.0f);
        }
      }
    }
  }
}

// out[i] = dot(h[a]*h[b], pwsum) + pwsum[128].  16 lanes/edge, 8 k each.
__global__ __launch_bounds__(256) void decoder_kernel(const float* __restrict__ h, const int* __restrict__ eli,
                                                      const float* __restrict__ pwsum, float* __restrict__ out, int M) {
  int t = threadIdx.x;
  int i = blockIdx.x * 16 + (t >> 4);
  int l = t & 15;
  if (i >= M) return;
  int a = eli[i], b = eli[M + i];
  int k = l * 8;
  const float4* ha = (const float4*)&h[(size_t)a * 128 + k];
  const float4* hb = (const float4*)&h[(size_t)b * 128 + k];
  float4 ha0 = ha[0], ha1 = ha[1];
  float4 hb0 = hb[0], hb1 = hb[1];
  const float4* pwp = (const float4*)&pwsum[k];
  float4 p0 = pwp[0], p1 = pwp[1];
  float s = 0.0f;
  s += ha0.x * hb0.x * p0.x;
  s += ha0.y * hb0.y * p0.y;
  s += ha0.z * hb0.z * p0.z;
  s += ha0.w * hb0.w * p0.w;
  s += ha1.x * hb1.x * p1.x;
  s += ha1.y * hb1.y * p1.y;
  s += ha1.z * hb1.z * p1.z;
  s += ha1.w * hb1.w * p1.w;
#pragma unroll
  for (int off = 8; off; off >>= 1) s += __shfl_xor(s, off);
  if (l == 0) out[i] = s + pwsum[128];
}

extern "C" void kernel_launch(void* const* d_in, const int* in_sizes, int n_in,
                              void* d_out, int out_size, void* d_ws, size_t ws_size,
                              hipStream_t stream) {
  const float* x      = (const float*)d_in[0];
  const int*   ei     = (const int*)d_in[1];
  const int*   eli    = (const int*)d_in[2];
  const float* pre_w  = (const float*)d_in[3];
  const float* pre_b  = (const float*)d_in[4];
  const float* Wx     = (const float*)d_in[5];
  const float* bx     = (const float*)d_in[6];
  const float* bh     = (const float*)d_in[8];
  const float* post_w = (const float*)d_in[9];
  const float* post_b = (const float*)d_in[10];
  float* out = (float*)d_out;

  const int N = in_sizes[0] / 128;
  const int E = in_sizes[1] / 2;
  const int M = in_sizes[2] / 2;
  const int RB = (N + 127) / 128;

  char* W = (char*)d_ws;
  size_t o = 0;
  int* deg = (int*)(W + o);  o += (size_t)N * 4;
  int* cur = (int*)(W + o);  o += (size_t)N * 4;
  int* ovfn = (int*)(W + o);
  size_t zbytes = o + 256;   o += 256;
  int* ovf = (int*)(W + o);  o += (size_t)OVF_MAX * 8;
  float* dinv = (float*)(W + o); o += (size_t)N * 4;
  o = (o + 255) & ~(size_t)255;
  int* bucket = (int*)(W + o);   o += (size_t)N * CAP * 4;
  o = (o + 255) & ~(size_t)255;
  unsigned short* Xhb = (unsigned short*)(W + o); o += (size_t)RB * 128 * 512;  // padded rows
  float* h = (float*)(W + o);    o += (size_t)N * 512;
  unsigned short* Bt1c = (unsigned short*)(W + o); o += 32768;
  unsigned short* Btc2 = (unsigned short*)(W + o); o += 131072;
  float* fb2 = (float*)(W + o);  o += 1024;
  float* pwsum = (float*)(W + o); o += 768;

  hipMemsetAsync(deg, 0, zbytes, stream);
  prep_kernel<<<322, 256, 0, stream>>>(pre_w, Wx, bx, bh, post_w, post_b, Bt1c, Btc2, fb2, pwsum);
  scatter_deg_kernel<<<(E + 255) / 256, 256, 0, stream>>>(ei, deg, cur, bucket, ovfn, ovf, E);
  dinv_kernel<<<(N + 255) / 256, 256, 0, stream>>>(deg, dinv, N);
  gemm1_mfma<<<RB, 256, 0, stream>>>(x, Bt1c, pre_b, Xhb, N);
  lap_gather<<<(N + 3) / 4, 256, 0, stream>>>(Xhb, bucket, cur, dinv, N);
  ovf_kernel<<<OVF_MAX / 256, 256, 0, stream>>>(Xhb, ovfn, ovf, dinv);
  gemm2_mfma<<<RB * 2, 256, 0, stream>>>(Xhb, Btc2, fb2, h, N);
  decoder_kernel<<<(M + 15) / 16, 256, 0, stream>>>(h, eli, pwsum, out, M);
}